// Round 5
// baseline (365.846 us; speedup 1.0000x reference)
//
#include <hip/hip_runtime.h>

// Problem constants (n = 8192 fixed by setup_inputs).
constexpr int NN   = 8192;
constexpr int ROWS = 32;              // rows per block tile
constexpr int COLS = 1024;            // cols per block tile (256 threads * 4)
constexpr int NBLK = (NN / ROWS) * (NN / COLS);   // 256 * 8 = 2048 blocks
constexpr int COPYBLKS = (NN * 3) / 256;          // 96 blocks copy pred_pos
constexpr int GROUPS = ROWS / 4;                  // software-pipeline granule

// ce = -mean( Q*log(P) + (1-Q)*log1p(-P) ),  Q = 1/w, w = max(1 + d2, 1),
// d2_ij = sq_i + sq_j - 2*dot(y_i,y_j).  rowC.x holds 1+sq_i so the +1 is free.
// Accumulate in log2 units; scale by -ln2/N^2 once.
//
// R4 lesson: TLP (blocks/occupancy/acc chains) did NOT hide cold-HBM latency;
// kernel stuck at ~110 us (~2.4 TB/s). This round: explicit 1-group-ahead
// register prefetch — compute of 4 rows (~1100 cyc) covers the ~900 cyc miss
// latency within a single wave.

__device__ __forceinline__ void bce4(const float4 p4, const float4 c,
                                     const float ya[4], const float yb[4],
                                     const float yc[4], const float sq[4],
                                     float acc[4])
{
    const float pp[4] = {p4.x, p4.y, p4.z, p4.w};
    #pragma unroll
    for (int e = 0; e < 4; ++e) {
        float w = c.x + sq[e];                  // (1+sq_i) + sq_j
        w = fmaf(c.y, ya[e], w);
        w = fmaf(c.z, yb[e], w);
        w = fmaf(c.w, yc[e], w);
        w = fmaxf(w, 1.0f);                     // == 1 + max(d2,0)
        const float q  = __builtin_amdgcn_rcpf(w);
        const float p  = fmaxf(pp[e], 1e-12f);
        const float lp = __log2f(p);
        const float lm = __log2f(1.0f - p);
        acc[e] = fmaf(q, lp - lm, acc[e] + lm);
    }
}

__global__ __launch_bounds__(256, 4)
void bce_tsne_kernel(const float* __restrict__ Pstar,
                     const float* __restrict__ pos,
                     float* __restrict__ out)
{
    __shared__ float4 rowC[ROWS];   // {1+sq_i, -2*y0, -2*y1, -2*y2}
    __shared__ float  waveSum[4];

    const int tid = threadIdx.x;
    const int bid = blockIdx.x;
    const int rowBase = (bid >> 3) * ROWS;    // NN/COLS == 8 col tiles
    const int colBase = (bid & 7) * COLS;

    if (tid < ROWS) {
        const int i = rowBase + tid;
        const float y0 = pos[i * 3 + 0];
        const float y1 = pos[i * 3 + 1];
        const float y2 = pos[i * 3 + 2];
        rowC[tid] = make_float4(fmaf(y0, y0, fmaf(y1, y1, fmaf(y2, y2, 1.0f))),
                                -2.0f * y0, -2.0f * y1, -2.0f * y2);
    }

    // Each thread owns 4 consecutive columns; y's live in registers.
    const int j0 = colBase + tid * 4;
    const float4 f0 = *(const float4*)(pos + (size_t)j0 * 3);
    const float4 f1 = *(const float4*)(pos + (size_t)j0 * 3 + 4);
    const float4 f2 = *(const float4*)(pos + (size_t)j0 * 3 + 8);
    float ya[4] = {f0.x, f0.w, f1.z, f2.y};
    float yb[4] = {f0.y, f1.x, f1.w, f2.z};
    float yc[4] = {f0.z, f1.y, f2.x, f2.w};
    float sq[4];
    #pragma unroll
    for (int e = 0; e < 4; ++e)
        sq[e] = fmaf(ya[e], ya[e], fmaf(yb[e], yb[e], yc[e] * yc[e]));

    __syncthreads();

    float acc[4] = {0.0f, 0.0f, 0.0f, 0.0f};
    const float* prow = Pstar + (size_t)rowBase * NN + j0;

    // Software pipeline: registers hold group g while group g+1 is in flight.
    float4 bufA[4];
    #pragma unroll
    for (int k = 0; k < 4; ++k)
        bufA[k] = *(const float4*)(prow + (size_t)k * NN);

    for (int g = 0; g < GROUPS - 1; ++g) {
        float4 bufB[4];
        const float* pn = prow + (size_t)(g + 1) * 4 * NN;
        #pragma unroll
        for (int k = 0; k < 4; ++k)                 // issue next group's loads
            bufB[k] = *(const float4*)(pn + (size_t)k * NN);
        #pragma unroll
        for (int k = 0; k < 4; ++k)                 // ~1100 cyc compute covers them
            bce4(bufA[k], rowC[g * 4 + k], ya, yb, yc, sq, acc);
        #pragma unroll
        for (int k = 0; k < 4; ++k) bufA[k] = bufB[k];
    }
    #pragma unroll
    for (int k = 0; k < 4; ++k)                     // epilogue: last group
        bce4(bufA[k], rowC[(GROUPS - 1) * 4 + k], ya, yb, yc, sq, acc);

    // Wave (64-lane) shuffle reduce, then cross-wave via LDS.
    float a = (acc[0] + acc[1]) + (acc[2] + acc[3]);
    #pragma unroll
    for (int off = 32; off > 0; off >>= 1)
        a += __shfl_down(a, off);
    const int lane = tid & 63;
    const int wid  = tid >> 6;
    if (lane == 0) waveSum[wid] = a;
    __syncthreads();
    if (tid == 0) {
        const float bp = waveSum[0] + waveSum[1] + waveSum[2] + waveSum[3];
        // scale: -ln2 / N^2  (log2-units -> natural log, negate, mean)
        atomicAdd(out, bp * (-0.69314718055994531f / 67108864.0f));
    }

    // Pass-through output: pred_pos -> out[1..24576]. Disjoint from out[0].
    if (bid < COPYBLKS) {
        const int k = bid * 256 + tid;
        out[1 + k] = pos[k];
    }
}

extern "C" void kernel_launch(void* const* d_in, const int* in_sizes, int n_in,
                              void* d_out, int out_size, void* d_ws, size_t ws_size,
                              hipStream_t stream) {
    const float* Pstar = (const float*)d_in[0];   // [8192*8192] f32
    const float* pos   = (const float*)d_in[1];   // [8192*3]    f32
    float* out = (float*)d_out;                   // [1 + 24576] f32

    // d_out is poisoned before every launch: zero the atomic accumulator.
    hipMemsetAsync(out, 0, sizeof(float), stream);
    bce_tsne_kernel<<<NBLK, 256, 0, stream>>>(Pstar, pos, out);
}

// Round 7
// 350.086 us; speedup vs baseline: 1.0450x; 1.0450x over previous
//
#include <hip/hip_runtime.h>

// Problem constants (n = 8192 fixed by setup_inputs).
constexpr int NN   = 8192;
constexpr int ROWS = 32;              // rows per block tile
constexpr int COLS = 1024;            // cols per block tile (256 threads * 4)
constexpr int NBLK = (NN / ROWS) * (NN / COLS);   // 256 * 8 = 2048 blocks
constexpr int COPYBLKS = (NN * 3) / 256;          // 96 blocks copy pred_pos

// Native vector type: __builtin_nontemporal_load needs a real vector, not
// HIP_vector_type (round-6 compile error).
typedef float floatx4 __attribute__((ext_vector_type(4)));

// ce = -mean( Q*log(P) + (1-Q)*log1p(-P) ),  Q = 1/w, w = max(1+d2, 1),
// d2_ij = sq_i + sq_j - 2*dot(y_i,y_j).  rowC.x holds 1+sq_i. Accumulate in
// log2 units; scale by -ln2/N^2 once at the end.
//
// R5 lesson: TLP, acc chains, and SW pipelining all left the kernel at
// ~110 us => not latency-bound. Theory: the harness's 1 GiB 0xAA ws-poison
// leaves ~256 MB DIRTY lines in L3; our cold read allocates L3 and forces
// dirty evictions => ~524 MB true HBM traffic. Fix: non-temporal (nt) loads
// for Pstar — read-once data, no L3 allocation, no forced writebacks.

__global__ __launch_bounds__(256, 4)
void bce_tsne_kernel(const float* __restrict__ Pstar,
                     const float* __restrict__ pos,
                     float* __restrict__ out)
{
    __shared__ float4 rowC[ROWS];   // {1+sq_i, -2*y0, -2*y1, -2*y2}
    __shared__ float  waveSum[4];

    const int tid = threadIdx.x;
    const int bid = blockIdx.x;
    const int rowBase = (bid >> 3) * ROWS;    // NN/COLS == 8 col tiles
    const int colBase = (bid & 7) * COLS;

    if (tid < ROWS) {
        const int i = rowBase + tid;
        const float y0 = pos[i * 3 + 0];
        const float y1 = pos[i * 3 + 1];
        const float y2 = pos[i * 3 + 2];
        rowC[tid] = make_float4(fmaf(y0, y0, fmaf(y1, y1, fmaf(y2, y2, 1.0f))),
                                -2.0f * y0, -2.0f * y1, -2.0f * y2);
    }

    // Each thread owns 4 consecutive columns; y components live in registers.
    const int j0 = colBase + tid * 4;
    const float4 f0 = *(const float4*)(pos + (size_t)j0 * 3);
    const float4 f1 = *(const float4*)(pos + (size_t)j0 * 3 + 4);
    const float4 f2 = *(const float4*)(pos + (size_t)j0 * 3 + 8);
    float ya[4] = {f0.x, f0.w, f1.z, f2.y};
    float yb[4] = {f0.y, f1.x, f1.w, f2.z};
    float yc[4] = {f0.z, f1.y, f2.x, f2.w};
    float sq[4];
    #pragma unroll
    for (int e = 0; e < 4; ++e)
        sq[e] = fmaf(ya[e], ya[e], fmaf(yb[e], yb[e], yc[e] * yc[e]));

    __syncthreads();

    float acc[4] = {0.0f, 0.0f, 0.0f, 0.0f};
    const float* prow = Pstar + (size_t)rowBase * NN + j0;

    #pragma unroll 4
    for (int r = 0; r < ROWS; ++r) {
        const float4 c = rowC[r];                  // LDS broadcast
        // Non-temporal 16B coalesced read: no L2/L3 allocation.
        const floatx4 p4 = __builtin_nontemporal_load(
                               (const floatx4*)(prow + (size_t)r * NN));
        const float pp[4] = {p4.x, p4.y, p4.z, p4.w};
        #pragma unroll
        for (int e = 0; e < 4; ++e) {
            float w = c.x + sq[e];                 // (1+sq_i) + sq_j
            w = fmaf(c.y, ya[e], w);
            w = fmaf(c.z, yb[e], w);
            w = fmaf(c.w, yc[e], w);
            w = fmaxf(w, 1.0f);                    // == 1 + max(d2,0)
            const float q  = __builtin_amdgcn_rcpf(w);
            const float p  = fmaxf(pp[e], 1e-12f); // upper clip no-op in fp32
            const float lp = __log2f(p);
            const float lm = __log2f(1.0f - p);
            acc[e] = fmaf(q, lp - lm, acc[e] + lm);
        }
    }

    // Wave (64-lane) shuffle reduce, then cross-wave via LDS.
    float a = (acc[0] + acc[1]) + (acc[2] + acc[3]);
    #pragma unroll
    for (int off = 32; off > 0; off >>= 1)
        a += __shfl_down(a, off);
    const int lane = tid & 63;
    const int wid  = tid >> 6;
    if (lane == 0) waveSum[wid] = a;
    __syncthreads();
    if (tid == 0) {
        const float bp = waveSum[0] + waveSum[1] + waveSum[2] + waveSum[3];
        // scale: -ln2 / N^2  (log2-units -> natural log, negate, mean)
        atomicAdd(out, bp * (-0.69314718055994531f / 67108864.0f));
    }

    // Pass-through output: pred_pos -> out[1..24576]. Disjoint from out[0].
    if (bid < COPYBLKS) {
        const int k = bid * 256 + tid;
        out[1 + k] = pos[k];
    }
}

extern "C" void kernel_launch(void* const* d_in, const int* in_sizes, int n_in,
                              void* d_out, int out_size, void* d_ws, size_t ws_size,
                              hipStream_t stream) {
    const float* Pstar = (const float*)d_in[0];   // [8192*8192] f32
    const float* pos   = (const float*)d_in[1];   // [8192*3]    f32
    float* out = (float*)d_out;                   // [1 + 24576] f32

    // d_out is poisoned before every launch: zero the atomic accumulator.
    (void)hipMemsetAsync(out, 0, sizeof(float), stream);
    bce_tsne_kernel<<<NBLK, 256, 0, stream>>>(Pstar, pos, out);
}

// Round 10
// 349.652 us; speedup vs baseline: 1.0463x; 1.0012x over previous
//
#include <hip/hip_runtime.h>

// Problem constants (n = 8192 fixed by setup_inputs).
constexpr int NN   = 8192;
constexpr int ROWS = 32;              // rows per block tile
constexpr int COLS = 1024;            // cols per block tile (256 threads * 4)
constexpr int NBLK = (NN / ROWS) * (NN / COLS);   // 256 * 8 = 2048 blocks
constexpr int COPYBLKS = (NN * 3) / 256;          // 96 blocks copy pred_pos

typedef float floatx4 __attribute__((ext_vector_type(4)));

// ce = -mean( Q*log(P) + (1-Q)*log1p(-P) ),  Q = 1/w, w = max(1+d2, 1).
// rowC.x holds 1+sq_i. Accumulate in log2 units; scale by -ln2/N^2 once.
//
// R7 lesson: NT loads gave only ~12 us (L2-evict avoidance; MALL still
// allocates). Kernel cold-read runs ~2.5 TB/s. This round: T1 XCD-chunked
// block swizzle — v = (bid%8)*256 + bid/8 (bijective, 2048%8==0) gives each
// XCD a private contiguous 32 MB row-arena: sequential DRAM streams, no
// 8-XCD re-fetch of the same window through the poison-thrashed MALL.

__global__ __launch_bounds__(256, 4)
void bce_tsne_kernel(const float* __restrict__ Pstar,
                     const float* __restrict__ pos,
                     float* __restrict__ out)
{
    __shared__ float4 rowC[ROWS];   // {1+sq_i, -2*y0, -2*y1, -2*y2}
    __shared__ float  waveSum[4];

    const int tid = threadIdx.x;
    const int bid = blockIdx.x;
    // XCD-aware bijective swizzle: blocks dispatched round-robin over 8 XCDs;
    // give XCD k the contiguous virtual range [k*256, (k+1)*256).
    const int v = (bid & 7) * (NBLK / 8) + (bid >> 3);
    const int rowBase = (v >> 3) * ROWS;      // NN/COLS == 8 col tiles
    const int colBase = (v & 7) * COLS;

    if (tid < ROWS) {
        const int i = rowBase + tid;
        const float y0 = pos[i * 3 + 0];
        const float y1 = pos[i * 3 + 1];
        const float y2 = pos[i * 3 + 2];
        rowC[tid] = make_float4(fmaf(y0, y0, fmaf(y1, y1, fmaf(y2, y2, 1.0f))),
                                -2.0f * y0, -2.0f * y1, -2.0f * y2);
    }

    // Each thread owns 4 consecutive columns; y components live in registers.
    const int j0 = colBase + tid * 4;
    const float4 f0 = *(const float4*)(pos + (size_t)j0 * 3);
    const float4 f1 = *(const float4*)(pos + (size_t)j0 * 3 + 4);
    const float4 f2 = *(const float4*)(pos + (size_t)j0 * 3 + 8);
    float ya[4] = {f0.x, f0.w, f1.z, f2.y};
    float yb[4] = {f0.y, f1.x, f1.w, f2.z};
    float yc[4] = {f0.z, f1.y, f2.x, f2.w};
    float sq[4];
    #pragma unroll
    for (int e = 0; e < 4; ++e)
        sq[e] = fmaf(ya[e], ya[e], fmaf(yb[e], yb[e], yc[e] * yc[e]));

    __syncthreads();

    float acc[4] = {0.0f, 0.0f, 0.0f, 0.0f};
    const float* prow = Pstar + (size_t)rowBase * NN + j0;

    #pragma unroll 4
    for (int r = 0; r < ROWS; ++r) {
        const float4 c = rowC[r];                  // LDS broadcast
        const floatx4 p4 = __builtin_nontemporal_load(
                               (const floatx4*)(prow + (size_t)r * NN));
        const float pp[4] = {p4.x, p4.y, p4.z, p4.w};
        #pragma unroll
        for (int e = 0; e < 4; ++e) {
            float w = c.x + sq[e];                 // (1+sq_i) + sq_j
            w = fmaf(c.y, ya[e], w);
            w = fmaf(c.z, yb[e], w);
            w = fmaf(c.w, yc[e], w);
            w = fmaxf(w, 1.0f);                    // == 1 + max(d2,0)
            const float q  = __builtin_amdgcn_rcpf(w);
            const float p  = fmaxf(pp[e], 1e-12f); // upper clip no-op in fp32
            const float lp = __log2f(p);
            const float lm = __log2f(1.0f - p);
            acc[e] = fmaf(q, lp - lm, acc[e] + lm);
        }
    }

    // Wave (64-lane) shuffle reduce, then cross-wave via LDS.
    float a = (acc[0] + acc[1]) + (acc[2] + acc[3]);
    #pragma unroll
    for (int off = 32; off > 0; off >>= 1)
        a += __shfl_down(a, off);
    const int lane = tid & 63;
    const int wid  = tid >> 6;
    if (lane == 0) waveSum[wid] = a;
    __syncthreads();
    if (tid == 0) {
        const float bp = waveSum[0] + waveSum[1] + waveSum[2] + waveSum[3];
        // scale: -ln2 / N^2  (log2-units -> natural log, negate, mean)
        atomicAdd(out, bp * (-0.69314718055994531f / 67108864.0f));
    }

    // Pass-through output: pred_pos -> out[1..24576]. Disjoint from out[0].
    if (bid < COPYBLKS) {
        const int k = bid * 256 + tid;
        out[1 + k] = pos[k];
    }
}

extern "C" void kernel_launch(void* const* d_in, const int* in_sizes, int n_in,
                              void* d_out, int out_size, void* d_ws, size_t ws_size,
                              hipStream_t stream) {
    const float* Pstar = (const float*)d_in[0];   // [8192*8192] f32
    const float* pos   = (const float*)d_in[1];   // [8192*3]    f32
    float* out = (float*)d_out;                   // [1 + 24576] f32

    // d_out is poisoned before every launch: zero the atomic accumulator.
    (void)hipMemsetAsync(out, 0, sizeof(float), stream);
    bce_tsne_kernel<<<NBLK, 256, 0, stream>>>(Pstar, pos, out);
}